// Round 1
// baseline (472.722 us; speedup 1.0000x reference)
//
#include <hip/hip_runtime.h>
#include <hip/hip_bf16.h>

#define VOCAB   65
#define SQRT_C  5.656854249492381f
#define BATCHES 65536
#define ROWS    (BATCHES * 8)
#define TABSZ   (8 * VOCAB * 32)       // 16640 floats per q/k/v table
#define PAIRS   (BATCHES / 2)          // 32768 batch-pairs (16 rows each)
#define NBLOCKS 2048
#define NWAVES  (NBLOCKS * 4)

typedef __attribute__((ext_vector_type(8))) short  short8;   // 8 bf16 = 4 VGPRs
typedef __attribute__((ext_vector_type(4))) float  float4v;  // MFMA C/D
typedef __attribute__((ext_vector_type(4))) int    intv4;    // 16B int load

__device__ __forceinline__ void wave_fence() {
    __asm__ volatile("s_waitcnt lgkmcnt(0)" ::: "memory");
}
__device__ __forceinline__ short bfbits(float f) {
    __hip_bfloat16 h = __float2bfloat16(f);
    return *reinterpret_cast<short*>(&h);
}
__device__ __forceinline__ float dot8(const float4 a0, const float4 a1,
                                      const float4 b0, const float4 b1) {
    return a0.x*b0.x + a0.y*b0.y + a0.z*b0.z + a0.w*b0.w
         + a1.x*b1.x + a1.y*b1.y + a1.z*b1.z + a1.w*b1.w;
}

// ---------------------------------------------------------------------------
// Kernel 1: precompute q/k/v tables over the 520 distinct (t, token) combos.
// tab[(t*65+tok)*32 + h*8 + d].  The faithful-bug score scale (* sqrt(C)) is
// folded into qtab so the fused kernel saves a multiply per score.
// ---------------------------------------------------------------------------
__global__ void qkv_table_kernel(const float* __restrict__ tok_emb,
                                 const float* __restrict__ pos_emb,
                                 const float* __restrict__ Wq,
                                 const float* __restrict__ Wk,
                                 const float* __restrict__ Wv,
                                 float* __restrict__ qtab,
                                 float* __restrict__ ktab,
                                 float* __restrict__ vtab) {
    int o = blockIdx.x * 256 + threadIdx.x;
    if (o >= 3 * TABSZ) return;
    int table = o / TABSZ;
    int r = o - table * TABSZ;
    int pair = r >> 5;
    int cd = r & 31;
    int t = pair / VOCAB;
    int tok = pair - t * VOCAB;
    int h = cd >> 3, d = cd & 7;
    const float* W = (table == 0) ? Wq : (table == 1) ? Wk : Wv;
    float acc = 0.f;
    #pragma unroll
    for (int c = 0; c < 32; ++c) {
        float xc = tok_emb[tok * 32 + c] + pos_emb[t * 32 + c];
        acc += xc * W[h * 256 + c * 8 + d];
    }
    if (table == 0) acc *= SQRT_C;     // faithful bug: scores * sqrt(C)
    float* tab = (table == 0) ? qtab : (table == 1) ? ktab : vtab;
    tab[r] = acc;
}

// ---------------------------------------------------------------------------
// Kernel 2: 4 independent waves per 256-block; each wave owns one batch-pair
// (16 logit rows) per iteration.
//  - K/V read per-lane straight from L2-resident tables (no LDS staging, no
//    fences, no token shuffles: 8 lanes per (b2,h) group share addresses).
//  - MLP + logits via bf16 MFMA 16x16x32 (x2 -> x3 transpose through LDS).
//  - Target logit extracted inline from Lc/L64 by predicate (no b6 gather).
//  - Logit stores + idx/target loads are non-temporal so the 136MB stream
//    does not evict the reused q/k/v tables from L2.
// ---------------------------------------------------------------------------
__global__ __launch_bounds__(256, 7) void fused_kernel(
        const int* __restrict__ idx, const int* __restrict__ targets,
        const float* __restrict__ qtab, const float* __restrict__ ktab,
        const float* __restrict__ vtab,
        const float* __restrict__ W_mlp,
        const float* __restrict__ b_mlp,
        const float* __restrict__ W_lm,
        const float* __restrict__ b_lm,
        float* __restrict__ out_logits,
        float* __restrict__ loss_acc) {
    // per-wave x3 bf16 [row][ch], row-stride 40 shorts (80B, 16B-aligned)
    __shared__ __align__(16) unsigned short sX3[4][640];

    const int tid = threadIdx.x;
    const int w = tid >> 6, l = tid & 63;
    const int q4 = l >> 4;        // MFMA quad
    const int n  = l & 15;        // MFMA col-lane / A-row
    const int t  = l & 7, b2 = (l >> 3) & 1, h = q4;   // attention identity

    // ---- persistent B-fragments: B[k=(q4*8+j)][n] ----
    short8 wmf[2], wlf[4], wlf4;
    #pragma unroll
    for (int c = 0; c < 2; ++c)
        #pragma unroll
        for (int j = 0; j < 8; ++j)
            wmf[c][j] = bfbits(W_mlp[(q4 * 8 + j) * 32 + c * 16 + n]);
    #pragma unroll
    for (int c = 0; c < 4; ++c)
        #pragma unroll
        for (int j = 0; j < 8; ++j)
            wlf[c][j] = bfbits(W_lm[(q4 * 8 + j) * VOCAB + c * 16 + n]);
    #pragma unroll
    for (int j = 0; j < 8; ++j)
        wlf4[j] = (n == 0) ? bfbits(W_lm[(q4 * 8 + j) * VOCAB + 64]) : (short)0;
    float bmc[2], blc[4];
    #pragma unroll
    for (int c = 0; c < 2; ++c) bmc[c] = b_mlp[c * 16 + n];
    #pragma unroll
    for (int c = 0; c < 4; ++c) blc[c] = b_lm[c * 16 + n];
    const float bl64 = b_lm[64];
    const float4v zf = {0.f, 0.f, 0.f, 0.f};

    float loss_local = 0.f;

    for (int pb = blockIdx.x * 4 + w; pb < PAIRS; pb += NWAVES) {
        const int rbase = pb * 16;

        // ---- tokens / targets: per-lane vector loads (wave-broadcast lines)
        const intv4 ta = __builtin_nontemporal_load(
            (const intv4*)(idx + rbase + b2 * 8));
        const intv4 tb = __builtin_nontemporal_load(
            (const intv4*)(idx + rbase + b2 * 8) + 1);
        const int tok_t = idx[rbase + b2 * 8 + t];          // own q token
        const intv4 tg = __builtin_nontemporal_load(
            (const intv4*)(targets + rbase + q4 * 4));      // epilogue rows

        // ---- q row (already * sqrt(C)) ----
        const float* qp = qtab + (t * VOCAB + tok_t) * 32 + h * 8;
        const float4 q0 = *(const float4*)(qp);
        const float4 q1 = *(const float4*)(qp + 4);

        const int toks[8] = {ta[0], ta[1], ta[2], ta[3],
                             tb[0], tb[1], tb[2], tb[3]};

        // ---- scores: per-lane K reads (8 distinct addrs per instruction) --
        float sc[8], m = -1e30f;
        #pragma unroll
        for (int s = 0; s < 8; ++s) {
            const float* kp = ktab + (s * VOCAB + toks[s]) * 32 + h * 8;
            float4 k0 = *(const float4*)(kp);
            float4 k1 = *(const float4*)(kp + 4);
            float d = dot8(q0, q1, k0, k1);
            sc[s] = d;
            if (s <= t) m = fmaxf(m, d);
        }
        float p[8], sum = 0.f;
        #pragma unroll
        for (int s = 0; s < 8; ++s) {
            p[s] = (s <= t) ? __expf(sc[s] - m) : 0.f;
            sum += p[s];
        }
        float inv = 1.f / sum;

        // ---- V accumulation ----
        float o[8];
        #pragma unroll
        for (int d = 0; d < 8; ++d) o[d] = 0.f;
        #pragma unroll
        for (int s = 0; s < 8; ++s) {
            const float* vp = vtab + (s * VOCAB + toks[s]) * 32 + h * 8;
            float4 v0 = *(const float4*)(vp);
            float4 v1 = *(const float4*)(vp + 4);
            o[0] += p[s] * v0.x; o[1] += p[s] * v0.y;
            o[2] += p[s] * v0.z; o[3] += p[s] * v0.w;
            o[4] += p[s] * v1.x; o[5] += p[s] * v1.y;
            o[6] += p[s] * v1.z; o[7] += p[s] * v1.w;
        }
        short8 a2;
        #pragma unroll
        for (int d = 0; d < 8; ++d) a2[d] = bfbits(o[d] * inv);

        // ---- MLP: x3 = relu(x2 @ W_mlp + b), 2 MFMAs ----
        float4v d0 = __builtin_amdgcn_mfma_f32_16x16x32_bf16(a2, wmf[0], zf, 0, 0, 0);
        float4v d1 = __builtin_amdgcn_mfma_f32_16x16x32_bf16(a2, wmf[1], zf, 0, 0, 0);
        #pragma unroll
        for (int i = 0; i < 4; ++i) {
            int row = q4 * 4 + i;
            sX3[w][row * 40 + n]      = (unsigned short)bfbits(fmaxf(d0[i] + bmc[0], 0.f));
            sX3[w][row * 40 + 16 + n] = (unsigned short)bfbits(fmaxf(d1[i] + bmc[1], 0.f));
        }
        wave_fence();
        // C->A transpose via LDS: one b128 read
        short8 a3 = *(const short8*)(&sX3[w][n * 40 + q4 * 8]);

        // ---- logits: 5 MFMAs (cols 0..63 + padded col-64 fragment) ----
        float4v Lc[4];
        #pragma unroll
        for (int c = 0; c < 4; ++c)
            Lc[c] = __builtin_amdgcn_mfma_f32_16x16x32_bf16(a3, wlf[c], zf, 0, 0, 0);
        float4v L64 = __builtin_amdgcn_mfma_f32_16x16x32_bf16(a3, wlf4, zf, 0, 0, 0);

        // ---- bias + nt-store + sum-exp + inline target pick ----
        float part[4] = {0.f, 0.f, 0.f, 0.f};
        #pragma unroll
        for (int c = 0; c < 4; ++c) {
            #pragma unroll
            for (int i = 0; i < 4; ++i) {
                float Lv = Lc[c][i] + blc[c];
                __builtin_nontemporal_store(
                    Lv, out_logits + (size_t)(rbase + q4 * 4 + i) * VOCAB + c * 16 + n);
                part[i] += __expf(Lv);
                if (c * 16 + n == tg[i]) loss_local -= Lv;   // exactly 1 lane/row
            }
        }
        if (n == 0) {
            #pragma unroll
            for (int i = 0; i < 4; ++i) {
                float Lv = L64[i] + bl64;
                __builtin_nontemporal_store(
                    Lv, out_logits + (size_t)(rbase + q4 * 4 + i) * VOCAB + 64);
                part[i] += __expf(Lv);
                if (tg[i] == 64) loss_local -= Lv;
            }
        }
        #pragma unroll
        for (int off = 1; off < 16; off <<= 1) {
            #pragma unroll
            for (int i = 0; i < 4; ++i) part[i] += __shfl_xor(part[i], off);
        }
        if (n == 0)
            loss_local += __logf(part[0]) + __logf(part[1])
                        + __logf(part[2]) + __logf(part[3]);
    }

    #pragma unroll
    for (int off = 1; off < 64; off <<= 1) loss_local += __shfl_xor(loss_local, off);
    if (l == 0) atomicAdd(loss_acc, loss_local);
}

__global__ void finalize_loss(const float* __restrict__ acc,
                              float* __restrict__ out) {
    out[0] = acc[0] * (1.f / (float)ROWS);
}

extern "C" void kernel_launch(void* const* d_in, const int* in_sizes, int n_in,
                              void* d_out, int out_size, void* d_ws, size_t ws_size,
                              hipStream_t stream) {
    const int* idx        = (const int*)d_in[0];
    const int* targets    = (const int*)d_in[1];
    const float* tok_emb  = (const float*)d_in[2];
    const float* pos_emb  = (const float*)d_in[3];
    const float* Wq       = (const float*)d_in[4];
    const float* Wk       = (const float*)d_in[5];
    const float* Wv       = (const float*)d_in[6];
    const float* W_mlp    = (const float*)d_in[7];
    const float* b_mlp    = (const float*)d_in[8];
    const float* W_lm     = (const float*)d_in[9];
    const float* b_lm     = (const float*)d_in[10];
    float* out            = (float*)d_out;

    float* ws       = (float*)d_ws;
    float* loss_ptr = ws;
    float* qtab     = ws + 16;
    float* ktab     = qtab + TABSZ;
    float* vtab     = ktab + TABSZ;

    hipMemsetAsync(loss_ptr, 0, sizeof(float), stream);

    qkv_table_kernel<<<(3 * TABSZ + 255) / 256, 256, 0, stream>>>(
        tok_emb, pos_emb, Wq, Wk, Wv, qtab, ktab, vtab);

    fused_kernel<<<NBLOCKS, 256, 0, stream>>>(
        idx, targets, qtab, ktab, vtab, W_mlp, b_mlp, W_lm, b_lm, out, loss_ptr);

    finalize_loss<<<1, 1, 0, stream>>>(loss_ptr, out + (size_t)ROWS * VOCAB);
}